// Round 17
// baseline (3484.531 us; speedup 1.0000x reference)
//
#include <hip/hip_runtime.h>

// ---------------------------------------------------------------------------
// RNN (LSTM) + CRF loss on MI355X — round 17.
// = round 16 with the EM stage deleted: 64 crf blocks poll lstm flags
// directly and compute their own emissions row in-block (h row staged to LDS,
// 512-FMA matvec per thread vs L2-resident WoutT). Removes em's ~100KB/step
// LLC traffic, the shared emflag hotspot, and one pipeline stage.
// Grid: 64 lstm + 64 crf = 128 blocks x 128 thr.
// LSTM role: r13/r16-proven, VERBATIM.
// ---------------------------------------------------------------------------

typedef float f32x4 __attribute__((ext_vector_type(4)));
typedef float f32x16 __attribute__((ext_vector_type(16)));
typedef __bf16 bf16x8 __attribute__((ext_vector_type(8)));
typedef unsigned int u32x4 __attribute__((ext_vector_type(4)));
typedef unsigned int u32x2 __attribute__((ext_vector_type(2)));

#define T_LEN 256
#define BB    64
#define EE    256
#define HH    512
#define KK    128
#define KCAT  768   // E + H

static __device__ inline unsigned f2bf(float f) {
  union { float f; unsigned u; } v; v.f = f;
  unsigned r = v.u + 0x7FFF + ((v.u >> 16) & 1);   // round-nearest-even
  return r >> 16;
}
static __device__ inline float bf2f(unsigned short u) {
  union { unsigned u; float f; } v; v.u = ((unsigned)u) << 16;
  return v.f;
}
static __device__ inline float sigm(float x) { return 1.f / (1.f + __expf(-x)); }
static __device__ inline float tanh_fast(float x) {
  return 1.f - 2.f / (1.f + __expf(2.f * x));      // safe at +/-inf
}
static __device__ inline bf16x8 ubf(u32x4 v) {
  union { u32x4 u; bf16x8 b; } c; c.u = v; return c.b;
}

// --- 1. weight conversion (LDS tile transpose, coalesced both sides) -------
__global__ __launch_bounds__(256) void build_wcat(
    const float* __restrict__ Wi, const float* __restrict__ Wh,
    unsigned short* __restrict__ WcatT) {
  __shared__ float tile[64][65];
  int ct = blockIdx.x & 31, kt = blockIdx.x >> 5;    // 32 c-tiles x 12 k-tiles
  int tc = threadIdx.x & 63, tr = threadIdx.x >> 6;
  int c0 = ct * 64, k0 = kt * 64;
#pragma unroll
  for (int i = 0; i < 16; ++i) {
    int r = tr * 16 + i, k = k0 + r;
    float v = (k < EE) ? Wi[(size_t)k * 2048 + c0 + tc]
                       : Wh[(size_t)(k - EE) * 2048 + c0 + tc];
    tile[r][tc] = v;
  }
  __syncthreads();
#pragma unroll
  for (int i = 0; i < 16; ++i) {
    int cL = tr * 16 + i;
    WcatT[(size_t)(c0 + cL) * KCAT + k0 + tc] = (unsigned short)f2bf(tile[tc][cL]);
  }
}

__global__ __launch_bounds__(256) void build_wout(
    const float* __restrict__ Wout, unsigned short* __restrict__ WoutT) {
  __shared__ float tile[64][65];
  int ct = blockIdx.x & 1, kt = blockIdx.x >> 1;     // 2 c-tiles x 8 k-tiles
  int tc = threadIdx.x & 63, tr = threadIdx.x >> 6;
  int c0 = ct * 64, k0 = kt * 64;
#pragma unroll
  for (int i = 0; i < 16; ++i) {
    int r = tr * 16 + i;
    tile[r][tc] = Wout[(size_t)(k0 + r) * KK + c0 + tc];
  }
  __syncthreads();
#pragma unroll
  for (int i = 0; i < 16; ++i) {
    int cL = tr * 16 + i;
    WoutT[(size_t)(c0 + cL) * HH + k0 + tc] = (unsigned short)f2bf(tile[tc][cL]);
  }
}

// --- 2. embedding ----------------------------------------------------------
__global__ __launch_bounds__(256) void embed_kernel(
    const int* __restrict__ wx, const int* __restrict__ cx,
    const float* __restrict__ we, const float* __restrict__ ce,
    unsigned short* __restrict__ x) {
  int bid = blockIdx.x;             // t*64 + b
  int t = bid >> 6, b = bid & 63;
  int e = threadIdx.x;              // 0..255
  int w = wx[b * T_LEN + t];
  float v = we[(size_t)w * EE + e];
  const int* cp = cx + ((size_t)(b * T_LEN + t)) * 8;
  float s = 0.f;
#pragma unroll
  for (int l = 0; l < 8; ++l) s += ce[(size_t)cp[l] * EE + e];
  v += s * 0.125f;
  x[(size_t)bid * EE + e] = (unsigned short)f2bf(v);
}

// --- 3. flag reset (64 lstm flags, sc1) -------------------------------------
__global__ void zero_flags(unsigned int* __restrict__ f) {
  unsigned z = 0u;
  asm volatile("global_store_dword %0, %1, off sc1"
               :: "v"(f + threadIdx.x), "v"(z) : "memory");
}

// --- 4. fused persistent kernel ---------------------------------------------
#define SBAR __builtin_amdgcn_sched_barrier(0)
#define WAITV(N) do { asm volatile("s_waitcnt vmcnt(" #N ")" ::: "memory"); SBAR; } while (0)
#define LDN(dst, ptr, OFF) \
  asm volatile("global_load_dwordx4 %0, %1, off offset:" OFF \
               : "=v"(dst) : "v"(ptr) : "memory")

#define ISSUE_X(B, P) do { \
  LDN(B[0],P,"0");   LDN(B[1],P,"32");  LDN(B[2],P,"64");  LDN(B[3],P,"96"); \
  LDN(B[4],P,"128"); LDN(B[5],P,"160"); LDN(B[6],P,"192"); LDN(B[7],P,"224"); \
  LDN(B[8],P,"256"); LDN(B[9],P,"288"); LDN(B[10],P,"320"); LDN(B[11],P,"352"); \
  LDN(B[12],P,"384"); LDN(B[13],P,"416"); LDN(B[14],P,"448"); LDN(B[15],P,"480"); } while (0)
#define ISSUE_H1(B, P) do { \
  LDN(B[0],P,"512"); LDN(B[1],P,"544"); LDN(B[2],P,"576"); LDN(B[3],P,"608"); \
  LDN(B[4],P,"640"); LDN(B[5],P,"672"); LDN(B[6],P,"704"); LDN(B[7],P,"736"); \
  LDN(B[8],P,"768"); LDN(B[9],P,"800"); LDN(B[10],P,"832"); LDN(B[11],P,"864"); \
  LDN(B[12],P,"896"); LDN(B[13],P,"928"); LDN(B[14],P,"960"); LDN(B[15],P,"992"); } while (0)

#define GATES_STORE(T) do { \
    bool mk = ((int)wxv) > 0; \
    _Pragma("unroll") \
    for (int r = 0; r < 4; ++r) { \
      float zi = acc[r], zf = acc[4 + r], zg = acc[8 + r], zo = acc[12 + r]; \
      float cn = sigm(zf) * cst[r] + sigm(zi) * tanh_fast(zg); \
      float hn = sigm(zo) * tanh_fast(cn); \
      if (mk) { cst[r] = cn; hst[r] = hn; } \
    } \
    u32x2 ph; \
    ph[0] = f2bf(hst[0]) | (f2bf(hst[1]) << 16); \
    ph[1] = f2bf(hst[2]) | (f2bf(hst[3]) << 16); \
    asm volatile("global_store_dwordx2 %0, %1, off sc1" \
                 :: "v"(hstore + (size_t)(T) * 65536), "v"(ph) : "memory"); \
  } while (0)

__global__ __launch_bounds__(128, 1) void fused_kernel(
    const unsigned short* __restrict__ x,      // [T][64][256] bf16
    unsigned short* __restrict__ hs,           // [256][64][512] bf16 (slot t = h[t+1])
    const unsigned short* __restrict__ WcatT,  // [2048][768] bf16
    const unsigned short* __restrict__ WoutT,  // [128][512] bf16
    const float* __restrict__ bias,            // [2048]
    const float* __restrict__ bout,            // [128]
    const float* __restrict__ trans,           // [128][128]
    const int* __restrict__ wx,                // [64][256]
    const int* __restrict__ y,                 // [64][257]
    unsigned int* __restrict__ flags,          // [64] lstm flags
    float* __restrict__ out) {                 // [64]
  __shared__ float s_El[KK][129];              // 66 KB
  __shared__ float s_h[HH];
  __shared__ float s_p[KK];
  __shared__ float s_red[4];
  __shared__ float s_redg[KK];

  const int bid = blockIdx.x;
  const int tid = threadIdx.x;
  const int wave = tid >> 6, lane = tid & 63;

  if (bid < 64) {
    // ================= LSTM role (r13/r16 verbatim) =================
    const int bhalf = wave;
    const int hi = lane >> 5;
    const int batch = bhalf * 32 + (lane & 31);
    const int u0 = bid * 8;
    const int rr = lane & 31;
    const int wcol = (rr >> 3) * HH + u0 + (rr & 7);

    bf16x8 wreg[48];
#pragma unroll
    for (int kf = 0; kf < 48; ++kf)
      wreg[kf] = *(const bf16x8*)(WcatT + (size_t)wcol * KCAT + kf * 16 + hi * 8);

    float bv[16];
#pragma unroll
    for (int q = 0; q < 4; ++q)
#pragma unroll
      for (int r = 0; r < 4; ++r)
        bv[q * 4 + r] = bias[q * HH + u0 + 4 * hi + r];

    const char* xlane  = (const char*)x  + ((size_t)batch * EE + hi * 8) * 2;
    const char* hread  = (const char*)hs + ((size_t)batch * HH + hi * 8) * 2;
    char*       hstore = (char*)hs + ((size_t)batch * HH + u0 + 4 * hi) * 2;
    const int*  wxp    = wx + batch * T_LEN;

    float cst[4] = {0.f, 0.f, 0.f, 0.f};
    float hst[4] = {0.f, 0.f, 0.f, 0.f};
    u32x4 bufX[16], bufH[16];
    unsigned wxv;
    f32x16 acc;

    // ---- t = 0 ----
    ISSUE_X(bufX, xlane);
    asm volatile("global_load_dword %0, %1, off" : "=v"(wxv) : "v"(wxp) : "memory");
    WAITV(0);
#pragma unroll
    for (int i = 0; i < 16; ++i) acc[i] = bv[i];
#pragma unroll
    for (int kf = 0; kf < 16; ++kf)
      acc = __builtin_amdgcn_mfma_f32_32x32x16_bf16(wreg[kf], ubf(bufX[kf]), acc, 0, 0, 0);
    GATES_STORE(0);
    WAITV(0);
    __syncthreads();
    if (tid == 0)
      __hip_atomic_store(flags + bid, 1u, __ATOMIC_RELAXED, __HIP_MEMORY_SCOPE_AGENT);

    // ---- t = 1..255 ----
    for (int t = 1; t < T_LEN; ++t) {
      const char* xt = xlane + (size_t)t * 32768;
      const char* hp = hread + (size_t)(t - 1) * 65536;

      ISSUE_X(bufX, xt);
      asm volatile("global_load_dword %0, %1, off" : "=v"(wxv) : "v"(wxp + t) : "memory");
      {
        unsigned v;
        do {
          asm volatile("global_load_dword %0, %1, off sc1\n\ts_waitcnt vmcnt(0)"
                       : "=v"(v) : "v"(flags + lane) : "memory");
        } while (!__all((int)(v >= (unsigned)t)));
        SBAR;
      }
      ISSUE_X(bufH, hp);                       // h chunk 0 (plain, L2-shared)
#pragma unroll
      for (int i = 0; i < 16; ++i) acc[i] = bv[i];
#pragma unroll
      for (int kf = 0; kf < 16; ++kf)
        acc = __builtin_amdgcn_mfma_f32_32x32x16_bf16(wreg[kf], ubf(bufX[kf]), acc, 0, 0, 0);
      SBAR;
      ISSUE_H1(bufX, hp);                      // h chunk 1 reuses x buffer
      WAITV(16);
#pragma unroll
      for (int kf = 0; kf < 16; ++kf)
        acc = __builtin_amdgcn_mfma_f32_32x32x16_bf16(wreg[16 + kf], ubf(bufH[kf]), acc, 0, 0, 0);
      WAITV(0);
#pragma unroll
      for (int kf = 0; kf < 16; ++kf)
        acc = __builtin_amdgcn_mfma_f32_32x32x16_bf16(wreg[32 + kf], ubf(bufX[kf]), acc, 0, 0, 0);
      GATES_STORE(t);
      WAITV(0);
      __syncthreads();
      if (tid == 0)
        __hip_atomic_store(flags + bid, (unsigned)(t + 1),
                           __ATOMIC_RELAXED, __HIP_MEMORY_SCOPE_AGENT);
    }
  } else {
    // ================= CRF role: b = bid - 64, 128 thr, k = tid ==========
    const int b = bid - 64;
    const int k = tid;                         // 0..127
    for (int i2 = tid; i2 < KK * KK; i2 += 128)
      s_El[i2 >> 7][i2 & 127] = __expf(trans[i2]);   // exp(-1e4) = 0
    __syncthreads();

    float sck = (k == 1) ? 0.f : -10000.f;
    float msc = 0.f, gold = 0.f;
    int len = 0;
    const char* wp = (const char*)WoutT + (size_t)k * HH * 2;

    for (int t = 0; t < T_LEN; ++t) {
      if (wx[b * T_LEN + t] <= 0) continue;    // block-uniform
      // poll all 64 lstm flags (per-wave; backoff: slack-rich)
      {
        unsigned v; int it = 0;
        for (;;) {
          asm volatile("global_load_dword %0, %1, off sc1\n\ts_waitcnt vmcnt(0)"
                       : "=v"(v) : "v"(flags + lane) : "memory");
          if (__all((int)(v >= (unsigned)(t + 1)))) break;
          if (++it >= (1 << 17)) break;        // fail visibly, never hang
          __builtin_amdgcn_s_sleep(2);
        }
        SBAR;
      }
      // stage h[t+1][b] row (plain loads: unique addrs, flag-ordered)
      {
        u32x2 hv = *(const u32x2*)(hs + ((size_t)t * BB + b) * HH + tid * 4);
        s_h[tid * 4]     = bf2f((unsigned short)(hv[0] & 0xffff));
        s_h[tid * 4 + 1] = bf2f((unsigned short)(hv[0] >> 16));
        s_h[tid * 4 + 2] = bf2f((unsigned short)(hv[1] & 0xffff));
        s_h[tid * 4 + 3] = bf2f((unsigned short)(hv[1] >> 16));
      }
      __syncthreads();
      // em_k = bout[k] + dot(h, WoutT[k][:]) — 512 FMA/thread, WoutT L2-hot
      float e = 0.f;
#pragma unroll 16
      for (int f = 0; f < 64; ++f) {
        u32x4 wv = *(const u32x4*)(wp + f * 16);
        const float* hb = s_h + f * 8;
#pragma unroll
        for (int d = 0; d < 4; ++d) {
          e += hb[d * 2]     * bf2f((unsigned short)(wv[d] & 0xffff));
          e += hb[d * 2 + 1] * bf2f((unsigned short)(wv[d] >> 16));
        }
      }
      float em_k = e + bout[k];
      // CRF step (E-precompute, r10/r14-proven math)
      s_p[k] = __expf(sck - msc);
      __syncthreads();
      float S = 0.f;
#pragma unroll
      for (int j = 0; j < KK; ++j) S += s_El[k][j] * s_p[j];
      float ns = em_k + msc + __logf(S);
      // gold (in-loop: em buffer no longer exists)
      int yn = y[b * 257 + t + 1];
      if (k == yn) gold += em_k + trans[yn * KK + y[b * 257 + t]];
      len++;
      sck = ns;
      // msc = max_k ns
      float m = ns;
#pragma unroll
      for (int off = 32; off; off >>= 1) m = fmaxf(m, __shfl_xor(m, off));
      if (lane == 0) s_red[wave] = m;
      __syncthreads();                         // also guards s_h/s_p reuse
      msc = fmaxf(s_red[0], s_red[1]);
    }

    // block-reduce gold (different yn threads accumulated different steps)
    s_redg[tid] = gold;
    __syncthreads();
    for (int s2 = 64; s2 > 0; s2 >>= 1) {
      if (tid < s2) s_redg[tid] += s_redg[tid + s2];
      __syncthreads();
    }
    gold = s_redg[0];
    __syncthreads();

    // Z = LSE_k(sc[k] + trans[EOS][k])
    float v = sck + trans[2 * KK + k];
    s_redg[tid] = v;
    __syncthreads();
    for (int s2 = 64; s2 > 0; s2 >>= 1) {
      if (tid < s2) s_redg[tid] = fmaxf(s_redg[tid], s_redg[tid + s2]);
      __syncthreads();
    }
    float mz = s_redg[0];
    __syncthreads();
    s_redg[tid] = __expf(v - mz);
    __syncthreads();
    for (int s2 = 64; s2 > 0; s2 >>= 1) {
      if (tid < s2) s_redg[tid] += s_redg[tid + s2];
      __syncthreads();
    }
    if (tid == 0) {
      float Z = mz + __logf(s_redg[0]);
      int last_tag = y[b * 257 + len];
      out[b] = Z - (gold + trans[2 * KK + last_tag]);
    }
  }
}

// ---------------------------------------------------------------------------
extern "C" void kernel_launch(void* const* d_in, const int* in_sizes, int n_in,
                              void* d_out, int out_size, void* d_ws, size_t ws_size,
                              hipStream_t stream) {
  const int*   cx    = (const int*)d_in[0];
  const int*   wx    = (const int*)d_in[1];
  const int*   y     = (const int*)d_in[2];
  const float* ce    = (const float*)d_in[3];
  const float* we    = (const float*)d_in[4];
  const float* Wi    = (const float*)d_in[5];
  const float* Wh    = (const float*)d_in[6];
  const float* bias  = (const float*)d_in[7];
  const float* Wout  = (const float*)d_in[8];
  const float* bout  = (const float*)d_in[9];
  const float* trans = (const float*)d_in[10];
  float* out = (float*)d_out;

  char* ws = (char*)d_ws;
  // ws layout (16B aligned), ~28.5 MB
  unsigned short* WcatT = (unsigned short*)(ws + 0);          //  3,145,728
  unsigned short* WoutT = (unsigned short*)(ws + 3145728);    //    131,072
  unsigned short* x     = (unsigned short*)(ws + 3276800);    //  8,388,608
  unsigned short* hs    = (unsigned short*)(ws + 11665408);   // 16,777,216
  unsigned int*   flags = (unsigned int*)(ws + 28442624);     //  64 dwords

  build_wcat<<<384, 256, 0, stream>>>(Wi, Wh, WcatT);
  build_wout<<<16, 256, 0, stream>>>(Wout, WoutT);
  embed_kernel<<<T_LEN * BB, 256, 0, stream>>>(wx, cx, we, ce, x);
  zero_flags<<<1, 64, 0, stream>>>(flags);
  fused_kernel<<<128, 128, 0, stream>>>(x, hs, WcatT, WoutT, bias, bout, trans,
                                        wx, y, flags, out);
}

// Round 18
// 1457.652 us; speedup vs baseline: 2.3905x; 2.3905x over previous
//
#include <hip/hip_runtime.h>

// ---------------------------------------------------------------------------
// RNN (LSTM) + CRF loss on MI355X — round 18 = round 16 (session best) verbatim.
// Persistent fused pipeline: 136 blocks x 128 thr.
//   bid 0-63 : LSTM (r13-proven: plain L2-shared h loads, sc1 stores, tight
//              flag poll, 192-VGPR resident weights, 32x32x16 swapped MFMA)
//   bid 64-71: em producers (poll lstm flags w/ backoff -> em[t] MFMA -> emflag)
//   bid 72-135: CRF per-batch (poll emflag w/ backoff -> E-precompute step)
// r17's in-chain emissions matvec regressed 2.4x (CRF chain became critical
// path at ~13.6us/step) — emissions restored to the pipelined em stage.
// ---------------------------------------------------------------------------

typedef float f32x4 __attribute__((ext_vector_type(4)));
typedef float f32x16 __attribute__((ext_vector_type(16)));
typedef __bf16 bf16x8 __attribute__((ext_vector_type(8)));
typedef unsigned int u32x4 __attribute__((ext_vector_type(4)));
typedef unsigned int u32x2 __attribute__((ext_vector_type(2)));

#define T_LEN 256
#define BB    64
#define EE    256
#define HH    512
#define KK    128
#define KCAT  768   // E + H

static __device__ inline unsigned f2bf(float f) {
  union { float f; unsigned u; } v; v.f = f;
  unsigned r = v.u + 0x7FFF + ((v.u >> 16) & 1);   // round-nearest-even
  return r >> 16;
}
static __device__ inline float sigm(float x) { return 1.f / (1.f + __expf(-x)); }
static __device__ inline float tanh_fast(float x) {
  return 1.f - 2.f / (1.f + __expf(2.f * x));      // safe at +/-inf
}
static __device__ inline bf16x8 ubf(u32x4 v) {
  union { u32x4 u; bf16x8 b; } c; c.u = v; return c.b;
}

// --- 1. weight conversion (LDS tile transpose, coalesced both sides) -------
__global__ __launch_bounds__(256) void build_wcat(
    const float* __restrict__ Wi, const float* __restrict__ Wh,
    unsigned short* __restrict__ WcatT) {
  __shared__ float tile[64][65];
  int ct = blockIdx.x & 31, kt = blockIdx.x >> 5;    // 32 c-tiles x 12 k-tiles
  int tc = threadIdx.x & 63, tr = threadIdx.x >> 6;
  int c0 = ct * 64, k0 = kt * 64;
#pragma unroll
  for (int i = 0; i < 16; ++i) {
    int r = tr * 16 + i, k = k0 + r;
    float v = (k < EE) ? Wi[(size_t)k * 2048 + c0 + tc]
                       : Wh[(size_t)(k - EE) * 2048 + c0 + tc];
    tile[r][tc] = v;
  }
  __syncthreads();
#pragma unroll
  for (int i = 0; i < 16; ++i) {
    int cL = tr * 16 + i;
    WcatT[(size_t)(c0 + cL) * KCAT + k0 + tc] = (unsigned short)f2bf(tile[tc][cL]);
  }
}

__global__ __launch_bounds__(256) void build_wout(
    const float* __restrict__ Wout, unsigned short* __restrict__ WoutT) {
  __shared__ float tile[64][65];
  int ct = blockIdx.x & 1, kt = blockIdx.x >> 1;     // 2 c-tiles x 8 k-tiles
  int tc = threadIdx.x & 63, tr = threadIdx.x >> 6;
  int c0 = ct * 64, k0 = kt * 64;
#pragma unroll
  for (int i = 0; i < 16; ++i) {
    int r = tr * 16 + i;
    tile[r][tc] = Wout[(size_t)(k0 + r) * KK + c0 + tc];
  }
  __syncthreads();
#pragma unroll
  for (int i = 0; i < 16; ++i) {
    int cL = tr * 16 + i;
    WoutT[(size_t)(c0 + cL) * HH + k0 + tc] = (unsigned short)f2bf(tile[tc][cL]);
  }
}

// --- 2. embedding ----------------------------------------------------------
__global__ __launch_bounds__(256) void embed_kernel(
    const int* __restrict__ wx, const int* __restrict__ cx,
    const float* __restrict__ we, const float* __restrict__ ce,
    unsigned short* __restrict__ x) {
  int bid = blockIdx.x;             // t*64 + b
  int t = bid >> 6, b = bid & 63;
  int e = threadIdx.x;              // 0..255
  int w = wx[b * T_LEN + t];
  float v = we[(size_t)w * EE + e];
  const int* cp = cx + ((size_t)(b * T_LEN + t)) * 8;
  float s = 0.f;
#pragma unroll
  for (int l = 0; l < 8; ++l) s += ce[(size_t)cp[l] * EE + e];
  v += s * 0.125f;
  x[(size_t)bid * EE + e] = (unsigned short)f2bf(v);
}

// --- 3. flag reset: 64 lstm flags + 256 em flags ---------------------------
__global__ void zero_flags(unsigned int* __restrict__ f) {
  int i = threadIdx.x;
  if (i < 320) {
    unsigned z = 0u;
    asm volatile("global_store_dword %0, %1, off sc1"
                 :: "v"(f + i), "v"(z) : "memory");
  }
}

// --- 4. fused persistent kernel ---------------------------------------------
#define SBAR __builtin_amdgcn_sched_barrier(0)
#define WAITV(N) do { asm volatile("s_waitcnt vmcnt(" #N ")" ::: "memory"); SBAR; } while (0)
#define LDN(dst, ptr, OFF) \
  asm volatile("global_load_dwordx4 %0, %1, off offset:" OFF \
               : "=v"(dst) : "v"(ptr) : "memory")

#define ISSUE_X(B, P) do { \
  LDN(B[0],P,"0");   LDN(B[1],P,"32");  LDN(B[2],P,"64");  LDN(B[3],P,"96"); \
  LDN(B[4],P,"128"); LDN(B[5],P,"160"); LDN(B[6],P,"192"); LDN(B[7],P,"224"); \
  LDN(B[8],P,"256"); LDN(B[9],P,"288"); LDN(B[10],P,"320"); LDN(B[11],P,"352"); \
  LDN(B[12],P,"384"); LDN(B[13],P,"416"); LDN(B[14],P,"448"); LDN(B[15],P,"480"); } while (0)
#define ISSUE_H1(B, P) do { \
  LDN(B[0],P,"512"); LDN(B[1],P,"544"); LDN(B[2],P,"576"); LDN(B[3],P,"608"); \
  LDN(B[4],P,"640"); LDN(B[5],P,"672"); LDN(B[6],P,"704"); LDN(B[7],P,"736"); \
  LDN(B[8],P,"768"); LDN(B[9],P,"800"); LDN(B[10],P,"832"); LDN(B[11],P,"864"); \
  LDN(B[12],P,"896"); LDN(B[13],P,"928"); LDN(B[14],P,"960"); LDN(B[15],P,"992"); } while (0)

#define GATES_STORE(T) do { \
    bool mk = ((int)wxv) > 0; \
    _Pragma("unroll") \
    for (int r = 0; r < 4; ++r) { \
      float zi = acc[r], zf = acc[4 + r], zg = acc[8 + r], zo = acc[12 + r]; \
      float cn = sigm(zf) * cst[r] + sigm(zi) * tanh_fast(zg); \
      float hn = sigm(zo) * tanh_fast(cn); \
      if (mk) { cst[r] = cn; hst[r] = hn; } \
    } \
    u32x2 ph; \
    ph[0] = f2bf(hst[0]) | (f2bf(hst[1]) << 16); \
    ph[1] = f2bf(hst[2]) | (f2bf(hst[3]) << 16); \
    asm volatile("global_store_dwordx2 %0, %1, off sc1" \
                 :: "v"(hstore + (size_t)(T) * 65536), "v"(ph) : "memory"); \
  } while (0)

__global__ __launch_bounds__(128, 1) void fused_kernel(
    const unsigned short* __restrict__ x,      // [T][64][256] bf16
    unsigned short* __restrict__ hs,           // [256][64][512] bf16 (slot t = h[t+1])
    const unsigned short* __restrict__ WcatT,  // [2048][768] bf16
    const unsigned short* __restrict__ WoutT,  // [128][512] bf16
    const float* __restrict__ bias,            // [2048]
    const float* __restrict__ bout,            // [128]
    const float* __restrict__ trans,           // [128][128]
    const int* __restrict__ wx,                // [64][256]
    const int* __restrict__ y,                 // [64][257]
    float* __restrict__ em,                    // [16384][128] f32
    unsigned int* __restrict__ flags,          // [64] lstm flags
    unsigned int* __restrict__ emflag,         // [256] em flags
    float* __restrict__ out) {                 // [64]
  __shared__ float s_tl[KK][129];
  __shared__ float s_El[KK][129];
  __shared__ float s_p[KK];
  __shared__ float s_red[16];

  const int bid = blockIdx.x;
  const int tid = threadIdx.x;
  const int wave = tid >> 6, lane = tid & 63;

  if (bid < 64) {
    // ================= LSTM role (r13 verbatim) =================
    const int bhalf = wave;
    const int hi = lane >> 5;
    const int batch = bhalf * 32 + (lane & 31);
    const int u0 = bid * 8;
    const int rr = lane & 31;
    const int wcol = (rr >> 3) * HH + u0 + (rr & 7);

    bf16x8 wreg[48];
#pragma unroll
    for (int kf = 0; kf < 48; ++kf)
      wreg[kf] = *(const bf16x8*)(WcatT + (size_t)wcol * KCAT + kf * 16 + hi * 8);

    float bv[16];
#pragma unroll
    for (int q = 0; q < 4; ++q)
#pragma unroll
      for (int r = 0; r < 4; ++r)
        bv[q * 4 + r] = bias[q * HH + u0 + 4 * hi + r];

    const char* xlane  = (const char*)x  + ((size_t)batch * EE + hi * 8) * 2;
    const char* hread  = (const char*)hs + ((size_t)batch * HH + hi * 8) * 2;
    char*       hstore = (char*)hs + ((size_t)batch * HH + u0 + 4 * hi) * 2;
    const int*  wxp    = wx + batch * T_LEN;

    float cst[4] = {0.f, 0.f, 0.f, 0.f};
    float hst[4] = {0.f, 0.f, 0.f, 0.f};
    u32x4 bufX[16], bufH[16];
    unsigned wxv;
    f32x16 acc;

    // ---- t = 0 ----
    ISSUE_X(bufX, xlane);
    asm volatile("global_load_dword %0, %1, off" : "=v"(wxv) : "v"(wxp) : "memory");
    WAITV(0);
#pragma unroll
    for (int i = 0; i < 16; ++i) acc[i] = bv[i];
#pragma unroll
    for (int kf = 0; kf < 16; ++kf)
      acc = __builtin_amdgcn_mfma_f32_32x32x16_bf16(wreg[kf], ubf(bufX[kf]), acc, 0, 0, 0);
    GATES_STORE(0);
    WAITV(0);
    __syncthreads();
    if (tid == 0)
      __hip_atomic_store(flags + bid, 1u, __ATOMIC_RELAXED, __HIP_MEMORY_SCOPE_AGENT);

    // ---- t = 1..255 ----
    for (int t = 1; t < T_LEN; ++t) {
      const char* xt = xlane + (size_t)t * 32768;
      const char* hp = hread + (size_t)(t - 1) * 65536;

      ISSUE_X(bufX, xt);
      asm volatile("global_load_dword %0, %1, off" : "=v"(wxv) : "v"(wxp + t) : "memory");
      {
        unsigned v;
        do {
          asm volatile("global_load_dword %0, %1, off sc1\n\ts_waitcnt vmcnt(0)"
                       : "=v"(v) : "v"(flags + lane) : "memory");
        } while (!__all((int)(v >= (unsigned)t)));
        SBAR;
      }
      ISSUE_X(bufH, hp);                       // h chunk 0 (plain, L2-shared)
#pragma unroll
      for (int i = 0; i < 16; ++i) acc[i] = bv[i];
#pragma unroll
      for (int kf = 0; kf < 16; ++kf)
        acc = __builtin_amdgcn_mfma_f32_32x32x16_bf16(wreg[kf], ubf(bufX[kf]), acc, 0, 0, 0);
      SBAR;
      ISSUE_H1(bufX, hp);                      // h chunk 1 reuses x buffer
      WAITV(16);
#pragma unroll
      for (int kf = 0; kf < 16; ++kf)
        acc = __builtin_amdgcn_mfma_f32_32x32x16_bf16(wreg[16 + kf], ubf(bufH[kf]), acc, 0, 0, 0);
      WAITV(0);
#pragma unroll
      for (int kf = 0; kf < 16; ++kf)
        acc = __builtin_amdgcn_mfma_f32_32x32x16_bf16(wreg[32 + kf], ubf(bufX[kf]), acc, 0, 0, 0);
      GATES_STORE(t);
      WAITV(0);
      __syncthreads();
      if (tid == 0)
        __hip_atomic_store(flags + bid, (unsigned)(t + 1),
                           __ATOMIC_RELAXED, __HIP_MEMORY_SCOPE_AGENT);
    }
  } else if (bid < 72) {
    // ================= EM role: t = (bid-64) + 8*i =================
    const int et0 = bid - 64;
    const int arow = lane & 15, kg4 = (lane >> 4) * 8;
    for (int i = 0; i < 32; ++i) {
      const int t = et0 + 8 * i;
      {
        unsigned v; int it = 0;
        for (;;) {
          asm volatile("global_load_dword %0, %1, off sc1\n\ts_waitcnt vmcnt(0)"
                       : "=v"(v) : "v"(flags + lane) : "memory");
          if (__all((int)(v >= (unsigned)(t + 1)))) break;
          if (++it >= (1 << 17)) break;        // fail visibly, never hang
          __builtin_amdgcn_s_sleep(2);         // backoff: slack-rich poll
        }
        SBAR;
      }
      const unsigned short* A0 = hs + ((size_t)t * BB + wave * 32 + arow) * HH + kg4;
      f32x4 acc2[2][8];
#pragma unroll
      for (int mt = 0; mt < 2; ++mt)
#pragma unroll
        for (int nt = 0; nt < 8; ++nt) acc2[mt][nt] = (f32x4){0.f, 0.f, 0.f, 0.f};
#pragma unroll
      for (int ks = 0; ks < 16; ++ks) {
        bf16x8 a0 = *(const bf16x8*)(A0 + ks * 32);
        bf16x8 a1 = *(const bf16x8*)(A0 + 16 * HH + ks * 32);
#pragma unroll
        for (int nt = 0; nt < 8; ++nt) {
          bf16x8 bf = *(const bf16x8*)(WoutT + (size_t)(nt * 16 + arow) * HH + kg4 + ks * 32);
          acc2[0][nt] = __builtin_amdgcn_mfma_f32_16x16x32_bf16(a0, bf, acc2[0][nt], 0, 0, 0);
          acc2[1][nt] = __builtin_amdgcn_mfma_f32_16x16x32_bf16(a1, bf, acc2[1][nt], 0, 0, 0);
        }
      }
      // store em[t] (no mask: masked-off entries are never read)
#pragma unroll
      for (int nt = 0; nt < 8; ++nt) {
        int n = nt * 16 + arow;
        float bo = bout[n];
#pragma unroll
        for (int mt = 0; mt < 2; ++mt)
#pragma unroll
          for (int r = 0; r < 4; ++r) {
            int row = t * BB + wave * 32 + mt * 16 + (lane >> 4) * 4 + r;
            float val = acc2[mt][nt][r] + bo;
            asm volatile("global_store_dword %0, %1, off sc1"
                         :: "v"(em + (size_t)row * KK + n), "v"(val) : "memory");
          }
      }
      WAITV(0);
      __syncthreads();
      if (tid == 0)
        __hip_atomic_store(emflag + t, 1u, __ATOMIC_RELAXED, __HIP_MEMORY_SCOPE_AGENT);
    }
  } else {
    // ================= CRF role: b = bid - 72 =================
    const int b = bid - 72;
    const int k = tid;                         // 0..127
    for (int i2 = tid; i2 < KK * KK; i2 += 128) {
      float v = trans[i2];
      s_tl[i2 >> 7][i2 & 127] = v;
      s_El[i2 >> 7][i2 & 127] = __expf(v);     // exp(-1e4) = 0
    }
    __syncthreads();
    float sck = (k == 1) ? 0.f : -10000.f;
    float msc = 0.f;

    for (int t = 0; t < T_LEN; ++t) {
      if (wx[b * T_LEN + t] <= 0) continue;    // block-uniform
      {
        unsigned v; int it = 0;
        for (;;) {
          asm volatile("global_load_dword %0, %1, off sc1\n\ts_waitcnt vmcnt(0)"
                       : "=v"(v) : "v"(emflag + t) : "memory");
          if (v) break;
          if (++it >= (1 << 17)) break;        // fail visibly, never hang
          __builtin_amdgcn_s_sleep(2);         // backoff: slack-rich poll
        }
        SBAR;
      }
      s_p[k] = __expf(sck - msc);
      __syncthreads();
      float S = 0.f;
#pragma unroll
      for (int j = 0; j < KK; ++j) S += s_El[k][j] * s_p[j];
      float ns = em[((size_t)t * BB + b) * KK + k] + msc + __logf(S);
      sck = ns;
      float m = ns;
#pragma unroll
      for (int off = 32; off; off >>= 1) m = fmaxf(m, __shfl_xor(m, off));
      if (lane == 0) s_red[8 + wave] = m;
      __syncthreads();                         // also guards s_p reuse next step
      msc = fmaxf(s_red[8], s_red[9]);
    }

    // gold score (all needed em[t] already flagged during the loop)
    float term = 0.f, cnt = 0.f;
#pragma unroll
    for (int rep = 0; rep < 2; ++rep) {
      int tt = tid + rep * 128;
      int yp = y[b * 257 + tt], yn = y[b * 257 + tt + 1];
      if (wx[b * T_LEN + tt] > 0) {
        term += em[((size_t)tt * BB + b) * KK + yn] + s_tl[yn][yp];
        cnt += 1.f;
      }
    }
#pragma unroll
    for (int off = 32; off; off >>= 1) {
      term += __shfl_xor(term, off);
      cnt += __shfl_xor(cnt, off);
    }
    if (lane == 0) { s_red[wave] = term; s_red[2 + wave] = cnt; }
    __syncthreads();
    float gold = s_red[0] + s_red[1];
    int len = (int)(s_red[2] + s_red[3] + 0.5f);

    // Z = LSE_k(sc[k] + trans[EOS][k])
    float v = sck + s_tl[2][k];
    float mz = v;
#pragma unroll
    for (int off = 32; off; off >>= 1) mz = fmaxf(mz, __shfl_xor(mz, off));
    if (lane == 0) s_red[4 + wave] = mz;
    __syncthreads();
    mz = fmaxf(s_red[4], s_red[5]);
    float e = __expf(v - mz);
#pragma unroll
    for (int off = 32; off; off >>= 1) e += __shfl_xor(e, off);
    if (lane == 0) s_red[6 + wave] = e;
    __syncthreads();
    if (tid == 0) {
      float Z = mz + __logf(s_red[6] + s_red[7]);
      int last_tag = y[b * 257 + len];
      out[b] = Z - (gold + s_tl[2][last_tag]);
    }
  }
}

// ---------------------------------------------------------------------------
extern "C" void kernel_launch(void* const* d_in, const int* in_sizes, int n_in,
                              void* d_out, int out_size, void* d_ws, size_t ws_size,
                              hipStream_t stream) {
  const int*   cx    = (const int*)d_in[0];
  const int*   wx    = (const int*)d_in[1];
  const int*   y     = (const int*)d_in[2];
  const float* ce    = (const float*)d_in[3];
  const float* we    = (const float*)d_in[4];
  const float* Wi    = (const float*)d_in[5];
  const float* Wh    = (const float*)d_in[6];
  const float* bias  = (const float*)d_in[7];
  const float* Wout  = (const float*)d_in[8];
  const float* bout  = (const float*)d_in[9];
  const float* trans = (const float*)d_in[10];
  float* out = (float*)d_out;

  char* ws = (char*)d_ws;
  // ws layout (16B aligned), ~37 MB
  unsigned short* WcatT = (unsigned short*)(ws + 0);          //  3,145,728
  unsigned short* WoutT = (unsigned short*)(ws + 3145728);    //    131,072
  unsigned short* x     = (unsigned short*)(ws + 3276800);    //  8,388,608
  unsigned short* hs    = (unsigned short*)(ws + 11665408);   // 16,777,216
  unsigned int*   flags = (unsigned int*)(ws + 28442624);     //  64 dwords
  unsigned int*   emflag= (unsigned int*)(ws + 28442880);     // 256 dwords
  float*          em    = (float*)(ws + 28444672);            //  8,388,608

  build_wcat<<<384, 256, 0, stream>>>(Wi, Wh, WcatT);
  build_wout<<<16, 256, 0, stream>>>(Wout, WoutT);
  embed_kernel<<<T_LEN * BB, 256, 0, stream>>>(wx, cx, we, ce, x);
  zero_flags<<<1, 320, 0, stream>>>(flags);
  fused_kernel<<<136, 128, 0, stream>>>(x, hs, WcatT, WoutT, bias, bout, trans,
                                        wx, y, em, flags, emflag, out);
}